// Round 1
// baseline (36.159 us; speedup 1.0000x reference)
//
#include <hip/hip_runtime.h>
#include <math.h>

#define LOG2E   1.4426950408889634f
#define SQRT2PI 2.5066282746310002f

__device__ __forceinline__ float tanh_fast(float z) {
  float az = fabsf(z);
  float u  = exp2f(-2.0f * LOG2E * az);   // exp(-2|z|)
  float r  = (1.0f - u) / (1.0f + u);
  return copysignf(r, z);
}

#define DOT4(acc, a, h)                                      \
  acc = fmaf((a).x, (h).x, acc); acc = fmaf((a).y, (h).y, acc); \
  acc = fmaf((a).z, (h).z, acc); acc = fmaf((a).w, (h).w, acc);

// ---------------------------------------------------------------------------
// Kernel 1: per-point MLP -> ws arrays {px, py, vx', vy'} (vx' = vx*valid*K)
// grid 256 blocks x 256 threads, 8 points/block (2048 points total)
// ---------------------------------------------------------------------------
__global__ __launch_bounds__(256) void mlp_kernel(
    const float* __restrict__ pts,                      // [2048][2]
    const float* __restrict__ W1, const float* __restrict__ b1,
    const float* __restrict__ W2, const float* __restrict__ b2,
    const float* __restrict__ W3, const float* __restrict__ b3,
    const float* __restrict__ Wf, const float* __restrict__ bf,
    const float* __restrict__ bw_p,
    float* __restrict__ wpx, float* __restrict__ wpy,
    float* __restrict__ wvx, float* __restrict__ wvy)
{
  __shared__ float sp[8][2];
  __shared__ float sh1[8][64];
  __shared__ float sh2[8][128];
  __shared__ float sh3[8][128];
  const int tid = threadIdx.x;
  const int p0  = blockIdx.x * 8;

  if (tid < 16) sp[tid >> 1][tid & 1] = pts[(p0 + (tid >> 1)) * 2 + (tid & 1)];
  __syncthreads();

  // layer 1: 2 -> 64, relu
  for (int t = tid; t < 8 * 64; t += 256) {
    int pt = t >> 6, o = t & 63;
    float h = fmaf(W1[o * 2 + 1], sp[pt][1], fmaf(W1[o * 2], sp[pt][0], b1[o]));
    sh1[pt][o] = fmaxf(h, 0.0f);
  }
  __syncthreads();

  // layer 2: 64 -> 128, relu   (thread o = tid&127 owns one output neuron)
  {
    const int o = tid & 127, g = tid >> 7;
    float4 w[16];
    const float4* wrow = (const float4*)(W2 + o * 64);
#pragma unroll
    for (int i = 0; i < 16; ++i) w[i] = wrow[i];
    const float bb = b2[o];
#pragma unroll
    for (int k = 0; k < 4; ++k) {
      const int pt = g * 4 + k;
      const float4* h4 = (const float4*)(&sh1[pt][0]);
      float acc = bb;
#pragma unroll
      for (int i = 0; i < 16; ++i) { float4 hh = h4[i]; DOT4(acc, w[i], hh); }
      sh2[pt][o] = fmaxf(acc, 0.0f);
    }
  }
  __syncthreads();

  // layer 3: 128 -> 128, no relu
  {
    const int o = tid & 127, g = tid >> 7;
    float4 w[32];
    const float4* wrow = (const float4*)(W3 + o * 128);
#pragma unroll
    for (int i = 0; i < 32; ++i) w[i] = wrow[i];
    const float bb = b3[o];
#pragma unroll
    for (int k = 0; k < 4; ++k) {
      const int pt = g * 4 + k;
      const float4* h4 = (const float4*)(&sh2[pt][0]);
      float acc = bb;
#pragma unroll
      for (int i = 0; i < 32; ++i) { float4 hh = h4[i]; DOT4(acc, w[i], hh); }
      sh3[pt][o] = acc;
    }
  }
  __syncthreads();

  // final: vecs = enc @ Wf.T + bf ; fold valid mask and K into vx', vy'
  if (tid < 16) {
    const int pt = tid >> 1, c = tid & 1;
    float acc = bf[c];
    const float4* wv = (const float4*)(Wf + c * 128);
    const float4* h4 = (const float4*)(&sh3[pt][0]);
#pragma unroll
    for (int i = 0; i < 32; ++i) { float4 a = wv[i]; float4 hh = h4[i]; DOT4(acc, a, hh); }
    const float px = sp[pt][0], py = sp[pt][1];
    const bool valid = (fabsf(px) > 1e-8f) || (fabsf(py) > 1e-8f);
    const float bw = fmaxf(bw_p[0], 1e-5f);
    const float K  = expf(-1e-8f / (2.0f * bw * bw));
    const float v  = valid ? acc * K : 0.0f;
    const int gp = p0 + pt;
    if (c == 0) { wvx[gp] = v; wpx[gp] = px; wpy[gp] = py; }
    else        { wvy[gp] = v; }
  }
}

// ---------------------------------------------------------------------------
// Kernel 2: separable KDE + field, one 32(y) x 128(x) tile per block.
// grid = 16 b * 8 ytiles * 2 xtiles = 256 blocks, 256 threads.
// LDS (dynamic, 112 KB): Ey/Vx/Vy [128][32] f32, Ex [128][128] f32
// ---------------------------------------------------------------------------
__global__ __launch_bounds__(256) void field_kernel(
    const float* __restrict__ wpx, const float* __restrict__ wpy,
    const float* __restrict__ wvx, const float* __restrict__ wvy,
    const float* __restrict__ bw_p, const float* __restrict__ thr_p,
    float* __restrict__ out)
{
  extern __shared__ float smem[];
  float (*Ey)[32]  = (float (*)[32])(smem);
  float (*Vx)[32]  = (float (*)[32])(smem + 128 * 32);
  float (*Vy)[32]  = (float (*)[32])(smem + 2 * 128 * 32);
  float (*Ex)[128] = (float (*)[128])(smem + 3 * 128 * 32);

  const int tid = threadIdx.x;
  const int bid = blockIdx.x;
  const int b   = bid >> 4;
  const int yt  = (bid >> 1) & 7;
  const int xt  = bid & 1;

  const float bw = fmaxf(bw_p[0], 1e-5f);
  const float c2 = -0.5f / (bw * bw) * LOG2E;   // exp2 exponent scale
  const float STEP = 2.0f / 255.0f;

  const float* px = wpx + b * 128;
  const float* py = wpy + b * 128;
  const float* vx = wvx + b * 128;
  const float* vy = wvy + b * 128;

  // Ey / Vx / Vy tables: 128 n x 32 yi
  for (int t = tid; t < 128 * 32; t += 256) {
    const int n = t >> 5, yi = t & 31;
    const float y  = fmaf((float)(yt * 32 + yi), STEP, -1.0f);
    const float dy = y - py[n];
    const float e  = exp2f(c2 * dy * dy);
    Ey[n][yi] = e;
    Vx[n][yi] = e * vx[n];
    Vy[n][yi] = e * vy[n];
  }
  // Ex table: 128 n x 128 xi
  for (int t = tid; t < 128 * 128; t += 256) {
    const int n = t >> 7, xi = t & 127;
    const float x  = fmaf((float)(xt * 128 + xi), STEP, -1.0f);
    const float dx = x - px[n];
    Ex[n][xi] = exp2f(c2 * dx * dx);
  }
  __syncthreads();

  // thread tile: 2 yi x 8 xi  (ty 0..15 -> yi pair; tx 0..15 -> 8 xi)
  const int ty = tid >> 4, tx = tid & 15;
  float aD[2][8] = {{0.0f}}, aX[2][8] = {{0.0f}}, aY[2][8] = {{0.0f}};

#pragma unroll 4
  for (int n = 0; n < 128; ++n) {
    const float2 ey = *(const float2*)&Ey[n][ty * 2];
    const float2 wx = *(const float2*)&Vx[n][ty * 2];
    const float2 wy = *(const float2*)&Vy[n][ty * 2];
    const float4 e0 = *(const float4*)&Ex[n][tx * 8];
    const float4 e1 = *(const float4*)&Ex[n][tx * 8 + 4];
    const float ex[8] = {e0.x, e0.y, e0.z, e0.w, e1.x, e1.y, e1.z, e1.w};
#pragma unroll
    for (int j = 0; j < 8; ++j) {
      aD[0][j] = fmaf(ey.x, ex[j], aD[0][j]);
      aX[0][j] = fmaf(wx.x, ex[j], aX[0][j]);
      aY[0][j] = fmaf(wy.x, ex[j], aY[0][j]);
      aD[1][j] = fmaf(ey.y, ex[j], aD[1][j]);
      aX[1][j] = fmaf(wx.y, ex[j], aX[1][j]);
      aY[1][j] = fmaf(wy.y, ex[j], aY[1][j]);
    }
  }

  const float thr      = thr_p[0];
  const float inv_norm = 1.0f / (128.0f * bw * SQRT2PI);
  const int yi0 = yt * 32 + ty * 2;
  const int xi0 = xt * 128 + tx * 8;
  float* outD = out;                                   // [16][1][256][256]
  float* outF = out + (size_t)16 * 256 * 256;          // [16][2][256][256]

#pragma unroll
  for (int r = 0; r < 2; ++r) {
    const int yi = yi0 + r;
    float td[8], tx8[8], ty8[8];
#pragma unroll
    for (int j = 0; j < 8; ++j) {
      const float dn = aD[r][j] * inv_norm;
      td[j]  = 1.0f / (1.0f + exp2f((thr - dn) * LOG2E));  // sigmoid(dn - thr)
      tx8[j] = tanh_fast(aX[r][j]);
      ty8[j] = tanh_fast(aY[r][j]);
    }
    const size_t dbase = (size_t)b * 65536 + (size_t)yi * 256 + xi0;
    *(float4*)&outD[dbase]     = make_float4(td[0], td[1], td[2], td[3]);
    *(float4*)&outD[dbase + 4] = make_float4(td[4], td[5], td[6], td[7]);
    const size_t fbase = (size_t)b * 131072 + (size_t)yi * 256 + xi0;
    *(float4*)&outF[fbase]             = make_float4(tx8[0], tx8[1], tx8[2], tx8[3]);
    *(float4*)&outF[fbase + 4]         = make_float4(tx8[4], tx8[5], tx8[6], tx8[7]);
    *(float4*)&outF[fbase + 65536]     = make_float4(ty8[0], ty8[1], ty8[2], ty8[3]);
    *(float4*)&outF[fbase + 65536 + 4] = make_float4(ty8[4], ty8[5], ty8[6], ty8[7]);
  }
}

// ---------------------------------------------------------------------------
extern "C" void kernel_launch(void* const* d_in, const int* in_sizes, int n_in,
                              void* d_out, int out_size, void* d_ws, size_t ws_size,
                              hipStream_t stream) {
  const float* pts = (const float*)d_in[0];
  const float* W1  = (const float*)d_in[1];
  const float* b1  = (const float*)d_in[2];
  const float* W2  = (const float*)d_in[3];
  const float* b2  = (const float*)d_in[4];
  const float* W3  = (const float*)d_in[5];
  const float* b3  = (const float*)d_in[6];
  const float* Wf  = (const float*)d_in[7];
  const float* bf  = (const float*)d_in[8];
  const float* bw  = (const float*)d_in[9];
  const float* thr = (const float*)d_in[10];

  float* ws  = (float*)d_ws;
  float* wpx = ws;
  float* wpy = ws + 2048;
  float* wvx = ws + 4096;
  float* wvy = ws + 6144;

  hipLaunchKernelGGL(mlp_kernel, dim3(256), dim3(256), 0, stream,
                     pts, W1, b1, W2, b2, W3, b3, Wf, bf, bw,
                     wpx, wpy, wvx, wvy);

  const size_t smem = (size_t)(3 * 128 * 32 + 128 * 128) * sizeof(float); // 112 KB
  hipLaunchKernelGGL(field_kernel, dim3(256), dim3(256), smem, stream,
                     wpx, wpy, wvx, wvy, bw, thr, (float*)d_out);
}

// Round 2
// 29.384 us; speedup vs baseline: 1.2306x; 1.2306x over previous
//
#include <hip/hip_runtime.h>
#include <math.h>

#define LOG2E   1.4426950408889634f
#define SQRT2PI 2.5066282746310002f

typedef _Float16 half8 __attribute__((ext_vector_type(8)));
typedef float    f32x4 __attribute__((ext_vector_type(4)));

__device__ __forceinline__ float tanh_fast(float z) {
  float az = fabsf(z);
  float u  = exp2f(-2.0f * LOG2E * az);   // exp(-2|z|)
  float r  = (1.0f - u) / (1.0f + u);
  return copysignf(r, z);
}

#define DOT4(acc, a, h)                                      \
  acc = fmaf((a).x, (h).x, acc); acc = fmaf((a).y, (h).y, acc); \
  acc = fmaf((a).z, (h).z, acc); acc = fmaf((a).w, (h).w, acc);

// ---------------------------------------------------------------------------
// Kernel 1: per-point MLP -> ws arrays {px, py, vx', vy'} (vx' = vx*valid*K)
// grid 256 blocks x 256 threads, 8 points/block (2048 points total)
// ---------------------------------------------------------------------------
__global__ __launch_bounds__(256) void mlp_kernel(
    const float* __restrict__ pts,                      // [2048][2]
    const float* __restrict__ W1, const float* __restrict__ b1,
    const float* __restrict__ W2, const float* __restrict__ b2,
    const float* __restrict__ W3, const float* __restrict__ b3,
    const float* __restrict__ Wf, const float* __restrict__ bf,
    const float* __restrict__ bw_p,
    float* __restrict__ wpx, float* __restrict__ wpy,
    float* __restrict__ wvx, float* __restrict__ wvy)
{
  __shared__ float sp[8][2];
  __shared__ float sh1[8][64];
  __shared__ float sh2[8][128];
  __shared__ float sh3[8][128];
  const int tid = threadIdx.x;
  const int p0  = blockIdx.x * 8;

  if (tid < 16) sp[tid >> 1][tid & 1] = pts[(p0 + (tid >> 1)) * 2 + (tid & 1)];
  __syncthreads();

  for (int t = tid; t < 8 * 64; t += 256) {
    int pt = t >> 6, o = t & 63;
    float h = fmaf(W1[o * 2 + 1], sp[pt][1], fmaf(W1[o * 2], sp[pt][0], b1[o]));
    sh1[pt][o] = fmaxf(h, 0.0f);
  }
  __syncthreads();

  {
    const int o = tid & 127, g = tid >> 7;
    float4 w[16];
    const float4* wrow = (const float4*)(W2 + o * 64);
#pragma unroll
    for (int i = 0; i < 16; ++i) w[i] = wrow[i];
    const float bb = b2[o];
#pragma unroll
    for (int k = 0; k < 4; ++k) {
      const int pt = g * 4 + k;
      const float4* h4 = (const float4*)(&sh1[pt][0]);
      float acc = bb;
#pragma unroll
      for (int i = 0; i < 16; ++i) { float4 hh = h4[i]; DOT4(acc, w[i], hh); }
      sh2[pt][o] = fmaxf(acc, 0.0f);
    }
  }
  __syncthreads();

  {
    const int o = tid & 127, g = tid >> 7;
    float4 w[32];
    const float4* wrow = (const float4*)(W3 + o * 128);
#pragma unroll
    for (int i = 0; i < 32; ++i) w[i] = wrow[i];
    const float bb = b3[o];
#pragma unroll
    for (int k = 0; k < 4; ++k) {
      const int pt = g * 4 + k;
      const float4* h4 = (const float4*)(&sh2[pt][0]);
      float acc = bb;
#pragma unroll
      for (int i = 0; i < 32; ++i) { float4 hh = h4[i]; DOT4(acc, w[i], hh); }
      sh3[pt][o] = acc;
    }
  }
  __syncthreads();

  if (tid < 16) {
    const int pt = tid >> 1, c = tid & 1;
    float acc = bf[c];
    const float4* wv = (const float4*)(Wf + c * 128);
    const float4* h4 = (const float4*)(&sh3[pt][0]);
#pragma unroll
    for (int i = 0; i < 32; ++i) { float4 a = wv[i]; float4 hh = h4[i]; DOT4(acc, a, hh); }
    const float px = sp[pt][0], py = sp[pt][1];
    const bool valid = (fabsf(px) > 1e-8f) || (fabsf(py) > 1e-8f);
    const float bw = fmaxf(bw_p[0], 1e-5f);
    const float K  = expf(-1e-8f / (2.0f * bw * bw));
    const float v  = valid ? acc * K : 0.0f;
    const int gp = p0 + pt;
    if (c == 0) { wvx[gp] = v; wpx[gp] = px; wpy[gp] = py; }
    else        { wvy[gp] = v; }
  }
}

// ---------------------------------------------------------------------------
// Kernel 2: build f16 tables, pixel-major x n:
//   Eyt[b][y][n] = exp(c*(y-py)^2), Vxt = Eyt*vx', Vyt = Eyt*vy',
//   Ext[b][x][n] = exp(c*(x-px)^2)
// grid 256 (= 16 img x 16 pixel-segments), 256 threads (16 pix x 16 n-groups)
// ---------------------------------------------------------------------------
__global__ __launch_bounds__(256) void tablegen_kernel(
    const float* __restrict__ wpx, const float* __restrict__ wpy,
    const float* __restrict__ wvx, const float* __restrict__ wvy,
    const float* __restrict__ bw_p,
    _Float16* __restrict__ Eyt, _Float16* __restrict__ Vxt,
    _Float16* __restrict__ Vyt, _Float16* __restrict__ Ext)
{
  const int b   = blockIdx.x >> 4;
  const int seg = blockIdx.x & 15;
  const int pr  = threadIdx.x >> 4;
  const int ng  = threadIdx.x & 15;
  const int pix = seg * 16 + pr;
  const float bw = fmaxf(bw_p[0], 1e-5f);
  const float c2 = -0.5f / (bw * bw) * LOG2E;
  const float STEP = 2.0f / 255.0f;
  const float g = fmaf((float)pix, STEP, -1.0f);
  const int nb = b * 128 + ng * 8;

  float px8[8], py8[8], vx8[8], vy8[8];
  *(float4*)&px8[0] = *(const float4*)&wpx[nb];
  *(float4*)&px8[4] = *(const float4*)&wpx[nb + 4];
  *(float4*)&py8[0] = *(const float4*)&wpy[nb];
  *(float4*)&py8[4] = *(const float4*)&wpy[nb + 4];
  *(float4*)&vx8[0] = *(const float4*)&wvx[nb];
  *(float4*)&vx8[4] = *(const float4*)&wvx[nb + 4];
  *(float4*)&vy8[0] = *(const float4*)&wvy[nb];
  *(float4*)&vy8[4] = *(const float4*)&wvy[nb + 4];

  half8 ey, vxe, vye, ex;
#pragma unroll
  for (int i = 0; i < 8; ++i) {
    const float dy = g - py8[i];
    const float e  = exp2f(c2 * dy * dy);
    ey[i]  = (_Float16)e;
    vxe[i] = (_Float16)(e * vx8[i]);
    vye[i] = (_Float16)(e * vy8[i]);
    const float dx = g - px8[i];
    ex[i]  = (_Float16)exp2f(c2 * dx * dx);
  }
  const size_t base = ((size_t)b * 256 + pix) * 128 + ng * 8;
  *(half8*)&Eyt[base] = ey;
  *(half8*)&Vxt[base] = vxe;
  *(half8*)&Vyt[base] = vye;
  *(half8*)&Ext[base] = ex;
}

// ---------------------------------------------------------------------------
// Kernel 3: MFMA field kernel. 512 blocks (16 img x 16 ytile x 2 xhalf),
// 256 threads = 4 waves; wave covers 32 columns (2 N-tiles of 16), 16 rows.
// No LDS. A = {Eyt,Vxt,Vyt} rows, B = Ext rows, K = 128 points.
// ---------------------------------------------------------------------------
__global__ __launch_bounds__(256) void field_mfma_kernel(
    const _Float16* __restrict__ Eyt, const _Float16* __restrict__ Vxt,
    const _Float16* __restrict__ Vyt, const _Float16* __restrict__ Ext,
    const float* __restrict__ bw_p, const float* __restrict__ thr_p,
    float* __restrict__ out)
{
  const int bid = blockIdx.x;          // [0, 512)
  const int b   = bid >> 5;
  const int yt  = (bid >> 1) & 15;
  const int xt  = bid & 1;
  const int wv   = threadIdx.x >> 6;
  const int lane = threadIdx.x & 63;
  const int lr = lane & 15, lg = lane >> 4;
  const int y0 = yt * 16;
  const int x0 = xt * 128 + wv * 32;

  const size_t tb   = (size_t)b * 256 * 128;
  const size_t arow = tb + (size_t)(y0 + lr) * 128 + lg * 8;
  const _Float16* pEy = Eyt + arow;
  const _Float16* pVx = Vxt + arow;
  const _Float16* pVy = Vyt + arow;
  const size_t brow0 = tb + (size_t)(x0 + lr) * 128 + lg * 8;
  const size_t brow1 = brow0 + 16 * 128;

  f32x4 acc[3][2];
#pragma unroll
  for (int c = 0; c < 3; ++c)
#pragma unroll
    for (int n = 0; n < 2; ++n) acc[c][n] = (f32x4){0.f, 0.f, 0.f, 0.f};

#pragma unroll
  for (int kk = 0; kk < 4; ++kk) {
    const int ko = kk * 32;
    const half8 aE = *(const half8*)(pEy + ko);
    const half8 aX = *(const half8*)(pVx + ko);
    const half8 aY = *(const half8*)(pVy + ko);
    const half8 b0 = *(const half8*)(Ext + brow0 + ko);
    const half8 b1 = *(const half8*)(Ext + brow1 + ko);
    acc[0][0] = __builtin_amdgcn_mfma_f32_16x16x32_f16(aE, b0, acc[0][0], 0, 0, 0);
    acc[1][0] = __builtin_amdgcn_mfma_f32_16x16x32_f16(aX, b0, acc[1][0], 0, 0, 0);
    acc[2][0] = __builtin_amdgcn_mfma_f32_16x16x32_f16(aY, b0, acc[2][0], 0, 0, 0);
    acc[0][1] = __builtin_amdgcn_mfma_f32_16x16x32_f16(aE, b1, acc[0][1], 0, 0, 0);
    acc[1][1] = __builtin_amdgcn_mfma_f32_16x16x32_f16(aX, b1, acc[1][1], 0, 0, 0);
    acc[2][1] = __builtin_amdgcn_mfma_f32_16x16x32_f16(aY, b1, acc[2][1], 0, 0, 0);
  }

  const float bw  = fmaxf(bw_p[0], 1e-5f);
  const float thr = thr_p[0];
  const float inv_norm = 1.0f / (128.0f * bw * SQRT2PI);
  float* outD = out;
  float* outF = out + (size_t)16 * 65536;

#pragma unroll
  for (int nt = 0; nt < 2; ++nt) {
    const int x = x0 + nt * 16 + lr;
#pragma unroll
    for (int r = 0; r < 4; ++r) {
      const int y = y0 + lg * 4 + r;
      const size_t pidx = (size_t)y * 256 + x;
      const float dn = acc[0][nt][r] * inv_norm;
      outD[(size_t)b * 65536 + pidx] = 1.0f / (1.0f + exp2f((thr - dn) * LOG2E));
      outF[(size_t)b * 131072 + pidx]         = tanh_fast(acc[1][nt][r]);
      outF[(size_t)b * 131072 + 65536 + pidx] = tanh_fast(acc[2][nt][r]);
    }
  }
}

// ---------------------------------------------------------------------------
extern "C" void kernel_launch(void* const* d_in, const int* in_sizes, int n_in,
                              void* d_out, int out_size, void* d_ws, size_t ws_size,
                              hipStream_t stream) {
  const float* pts = (const float*)d_in[0];
  const float* W1  = (const float*)d_in[1];
  const float* b1  = (const float*)d_in[2];
  const float* W2  = (const float*)d_in[3];
  const float* b2  = (const float*)d_in[4];
  const float* W3  = (const float*)d_in[5];
  const float* b3  = (const float*)d_in[6];
  const float* Wf  = (const float*)d_in[7];
  const float* bf  = (const float*)d_in[8];
  const float* bw  = (const float*)d_in[9];
  const float* thr = (const float*)d_in[10];

  float* ws  = (float*)d_ws;
  float* wpx = ws;
  float* wpy = ws + 2048;
  float* wvx = ws + 4096;
  float* wvy = ws + 6144;
  _Float16* Eyt = (_Float16*)(ws + 8192);   // 16*256*128 halves = 1 MB each
  _Float16* Vxt = Eyt + 524288;
  _Float16* Vyt = Vxt + 524288;
  _Float16* Ext = Vyt + 524288;

  hipLaunchKernelGGL(mlp_kernel, dim3(256), dim3(256), 0, stream,
                     pts, W1, b1, W2, b2, W3, b3, Wf, bf, bw,
                     wpx, wpy, wvx, wvy);

  hipLaunchKernelGGL(tablegen_kernel, dim3(256), dim3(256), 0, stream,
                     wpx, wpy, wvx, wvy, bw, Eyt, Vxt, Vyt, Ext);

  hipLaunchKernelGGL(field_mfma_kernel, dim3(512), dim3(256), 0, stream,
                     Eyt, Vxt, Vyt, Ext, bw, thr, (float*)d_out);
}

// Round 3
// 27.656 us; speedup vs baseline: 1.3075x; 1.0625x over previous
//
#include <hip/hip_runtime.h>
#include <math.h>

#define LOG2E   1.4426950408889634f
#define SQRT2PI 2.5066282746310002f

typedef _Float16 half8 __attribute__((ext_vector_type(8)));
typedef float    f32x4 __attribute__((ext_vector_type(4)));

__device__ __forceinline__ float rcp_fast(float x) { return __builtin_amdgcn_rcpf(x); }

__device__ __forceinline__ float tanh_fast(float z) {
  float az = fabsf(z);
  float u  = exp2f(-2.0f * LOG2E * az);   // exp(-2|z|)
  float r  = (1.0f - u) * rcp_fast(1.0f + u);
  return copysignf(r, z);
}

#define DOT4(acc, a, h)                                        \
  acc = fmaf((a).x, (h).x, acc); acc = fmaf((a).y, (h).y, acc); \
  acc = fmaf((a).z, (h).z, acc); acc = fmaf((a).w, (h).w, acc);

// ---------------------------------------------------------------------------
// Kernel 1: fused MLP + table slice generation.
// 256 blocks = (image b in 0..15) x (slice q in 0..15); 8 points per block.
// Block computes its 8 points' MLP outputs, then writes the n-slice
// [b][pix][8q .. 8q+8) of all four f16 tables for all 256 pixel coords.
// No cross-block dependencies.
// ---------------------------------------------------------------------------
__global__ __launch_bounds__(256) void mlp_table_kernel(
    const float* __restrict__ pts,                      // [2048][2]
    const float* __restrict__ W1, const float* __restrict__ b1,
    const float* __restrict__ W2, const float* __restrict__ b2,
    const float* __restrict__ W3, const float* __restrict__ b3,
    const float* __restrict__ Wf, const float* __restrict__ bf,
    const float* __restrict__ bw_p,
    _Float16* __restrict__ Eyt, _Float16* __restrict__ Vxt,
    _Float16* __restrict__ Vyt, _Float16* __restrict__ Ext)
{
  __shared__ float sp[8][2];
  __shared__ float sh1[8][64];
  __shared__ float sh2[8][128];
  __shared__ float sh3[8][128];
  __shared__ float sfin[8][2];
  const int tid = threadIdx.x;
  const int b   = blockIdx.x >> 4;
  const int q   = blockIdx.x & 15;
  const int p0  = b * 128 + q * 8;

  if (tid < 16) sp[tid >> 1][tid & 1] = pts[(p0 + (tid >> 1)) * 2 + (tid & 1)];
  __syncthreads();

  // layer 1: 2 -> 64, relu
  for (int t = tid; t < 8 * 64; t += 256) {
    int pt = t >> 6, o = t & 63;
    float h = fmaf(W1[o * 2 + 1], sp[pt][1], fmaf(W1[o * 2], sp[pt][0], b1[o]));
    sh1[pt][o] = fmaxf(h, 0.0f);
  }
  __syncthreads();

  // layer 2: 64 -> 128, relu (thread owns neuron o for 4 points)
  {
    const int o = tid & 127, g = tid >> 7;
    float4 w[16];
    const float4* wrow = (const float4*)(W2 + o * 64);
#pragma unroll
    for (int i = 0; i < 16; ++i) w[i] = wrow[i];
    float acc[4];
#pragma unroll
    for (int j = 0; j < 4; ++j) acc[j] = b2[o];
#pragma unroll
    for (int i = 0; i < 16; ++i) {
      const float4 ww = w[i];
#pragma unroll
      for (int j = 0; j < 4; ++j) {
        const float4 hh = *(const float4*)&sh1[g * 4 + j][i * 4];
        DOT4(acc[j], ww, hh);
      }
    }
#pragma unroll
    for (int j = 0; j < 4; ++j) sh2[g * 4 + j][o] = fmaxf(acc[j], 0.0f);
  }
  __syncthreads();

  // layer 3: 128 -> 128, no relu
  {
    const int o = tid & 127, g = tid >> 7;
    float4 w[32];
    const float4* wrow = (const float4*)(W3 + o * 128);
#pragma unroll
    for (int i = 0; i < 32; ++i) w[i] = wrow[i];
    float acc[4];
#pragma unroll
    for (int j = 0; j < 4; ++j) acc[j] = b3[o];
#pragma unroll
    for (int i = 0; i < 32; ++i) {
      const float4 ww = w[i];
#pragma unroll
      for (int j = 0; j < 4; ++j) {
        const float4 hh = *(const float4*)&sh2[g * 4 + j][i * 4];
        DOT4(acc[j], ww, hh);
      }
    }
#pragma unroll
    for (int j = 0; j < 4; ++j) sh3[g * 4 + j][o] = acc[j];
  }
  __syncthreads();

  // final 128 -> 2, fold valid mask and exp(-1e-8/(2 bw^2)) into vx', vy'
  if (tid < 16) {
    const int pt = tid >> 1, c = tid & 1;
    float acc = bf[c];
    const float4* wv = (const float4*)(Wf + c * 128);
    const float4* h4 = (const float4*)&sh3[pt][0];
#pragma unroll
    for (int i = 0; i < 32; ++i) { float4 a = wv[i]; float4 hh = h4[i]; DOT4(acc, a, hh); }
    const float px = sp[pt][0], py = sp[pt][1];
    const bool valid = (fabsf(px) > 1e-8f) || (fabsf(py) > 1e-8f);
    const float bw = fmaxf(bw_p[0], 1e-5f);
    const float K  = expf(-1e-8f / (2.0f * bw * bw));
    sfin[pt][c] = valid ? acc * K : 0.0f;
  }
  __syncthreads();

  // table slice: thread = pixel coordinate (0..255), n in [8q, 8q+8)
  {
    const float bw = fmaxf(bw_p[0], 1e-5f);
    const float c2 = -0.5f / (bw * bw) * LOG2E;
    const float STEP = 2.0f / 255.0f;
    const float g = fmaf((float)tid, STEP, -1.0f);
    half8 ey, vxe, vye, ex;
#pragma unroll
    for (int j = 0; j < 8; ++j) {
      const float dy = g - sp[j][1];
      const float e  = exp2f(c2 * dy * dy);
      ey[j]  = (_Float16)e;
      vxe[j] = (_Float16)(e * sfin[j][0]);
      vye[j] = (_Float16)(e * sfin[j][1]);
      const float dx = g - sp[j][0];
      ex[j]  = (_Float16)exp2f(c2 * dx * dx);
    }
    const size_t base = ((size_t)b * 256 + tid) * 128 + q * 8;
    *(half8*)&Eyt[base] = ey;
    *(half8*)&Vxt[base] = vxe;
    *(half8*)&Vyt[base] = vye;
    *(half8*)&Ext[base] = ex;
  }
}

// ---------------------------------------------------------------------------
// Kernel 2: MFMA field kernel. 512 blocks (16 img x 16 ytile x 2 xhalf),
// 256 threads = 4 waves; wave covers 32 columns (2 N-tiles of 16), 16 rows.
// No LDS. A = {Eyt,Vxt,Vyt} rows, B = Ext rows, K = 128 points.
// ---------------------------------------------------------------------------
__global__ __launch_bounds__(256) void field_mfma_kernel(
    const _Float16* __restrict__ Eyt, const _Float16* __restrict__ Vxt,
    const _Float16* __restrict__ Vyt, const _Float16* __restrict__ Ext,
    const float* __restrict__ bw_p, const float* __restrict__ thr_p,
    float* __restrict__ out)
{
  const int bid = blockIdx.x;          // [0, 512)
  const int b   = bid >> 5;
  const int yt  = (bid >> 1) & 15;
  const int xt  = bid & 1;
  const int wv   = threadIdx.x >> 6;
  const int lane = threadIdx.x & 63;
  const int lr = lane & 15, lg = lane >> 4;
  const int y0 = yt * 16;
  const int x0 = xt * 128 + wv * 32;

  const size_t tb   = (size_t)b * 256 * 128;
  const size_t arow = tb + (size_t)(y0 + lr) * 128 + lg * 8;
  const _Float16* pEy = Eyt + arow;
  const _Float16* pVx = Vxt + arow;
  const _Float16* pVy = Vyt + arow;
  const size_t brow0 = tb + (size_t)(x0 + lr) * 128 + lg * 8;
  const size_t brow1 = brow0 + 16 * 128;

  f32x4 acc[3][2];
#pragma unroll
  for (int c = 0; c < 3; ++c)
#pragma unroll
    for (int n = 0; n < 2; ++n) acc[c][n] = (f32x4){0.f, 0.f, 0.f, 0.f};

#pragma unroll
  for (int kk = 0; kk < 4; ++kk) {
    const int ko = kk * 32;
    const half8 aE = *(const half8*)(pEy + ko);
    const half8 aX = *(const half8*)(pVx + ko);
    const half8 aY = *(const half8*)(pVy + ko);
    const half8 b0 = *(const half8*)(Ext + brow0 + ko);
    const half8 b1 = *(const half8*)(Ext + brow1 + ko);
    acc[0][0] = __builtin_amdgcn_mfma_f32_16x16x32_f16(aE, b0, acc[0][0], 0, 0, 0);
    acc[1][0] = __builtin_amdgcn_mfma_f32_16x16x32_f16(aX, b0, acc[1][0], 0, 0, 0);
    acc[2][0] = __builtin_amdgcn_mfma_f32_16x16x32_f16(aY, b0, acc[2][0], 0, 0, 0);
    acc[0][1] = __builtin_amdgcn_mfma_f32_16x16x32_f16(aE, b1, acc[0][1], 0, 0, 0);
    acc[1][1] = __builtin_amdgcn_mfma_f32_16x16x32_f16(aX, b1, acc[1][1], 0, 0, 0);
    acc[2][1] = __builtin_amdgcn_mfma_f32_16x16x32_f16(aY, b1, acc[2][1], 0, 0, 0);
  }

  const float bw  = fmaxf(bw_p[0], 1e-5f);
  const float thr = thr_p[0];
  const float inv_norm = 1.0f / (128.0f * bw * SQRT2PI);
  float* outD = out;
  float* outF = out + (size_t)16 * 65536;

#pragma unroll
  for (int nt = 0; nt < 2; ++nt) {
    const int x = x0 + nt * 16 + lr;
#pragma unroll
    for (int r = 0; r < 4; ++r) {
      const int y = y0 + lg * 4 + r;
      const size_t pidx = (size_t)y * 256 + x;
      const float dn = acc[0][nt][r] * inv_norm;
      outD[(size_t)b * 65536 + pidx] = rcp_fast(1.0f + exp2f((thr - dn) * LOG2E));
      outF[(size_t)b * 131072 + pidx]         = tanh_fast(acc[1][nt][r]);
      outF[(size_t)b * 131072 + 65536 + pidx] = tanh_fast(acc[2][nt][r]);
    }
  }
}

// ---------------------------------------------------------------------------
extern "C" void kernel_launch(void* const* d_in, const int* in_sizes, int n_in,
                              void* d_out, int out_size, void* d_ws, size_t ws_size,
                              hipStream_t stream) {
  const float* pts = (const float*)d_in[0];
  const float* W1  = (const float*)d_in[1];
  const float* b1  = (const float*)d_in[2];
  const float* W2  = (const float*)d_in[3];
  const float* b2  = (const float*)d_in[4];
  const float* W3  = (const float*)d_in[5];
  const float* b3  = (const float*)d_in[6];
  const float* Wf  = (const float*)d_in[7];
  const float* bf  = (const float*)d_in[8];
  const float* bw  = (const float*)d_in[9];
  const float* thr = (const float*)d_in[10];

  _Float16* Eyt = (_Float16*)d_ws;          // 16*256*128 halves = 1 MB each
  _Float16* Vxt = Eyt + 524288;
  _Float16* Vyt = Vxt + 524288;
  _Float16* Ext = Vyt + 524288;

  hipLaunchKernelGGL(mlp_table_kernel, dim3(256), dim3(256), 0, stream,
                     pts, W1, b1, W2, b2, W3, b3, Wf, bf, bw,
                     Eyt, Vxt, Vyt, Ext);

  hipLaunchKernelGGL(field_mfma_kernel, dim3(512), dim3(256), 0, stream,
                     Eyt, Vxt, Vyt, Ext, bw, thr, (float*)d_out);
}